// Round 20
// baseline (9152.558 us; speedup 1.0000x reference)
//
#include <hip/hip_runtime.h>

// ZoneoutGRU persistent kernel v27: B=64, T=1024, IN=512, H=1024, L=2, zo=0.1.
// 128 active blocks (64 LA, 64 LB), 256 thr. Mailbox sync (v12), plain
// cached stream loads (v14), waves_per_eu(1,1) (v16), rule-#20 weight fix
// (v18), LB wave role-split (v26 = best, 7.67ms).
// v27 vs v26 — ONE change: LA x-GEMM HOISTED before the mailbox wait.
//   v26's null (removing LB's whole a-segment moved nothing) implies LB has
//   slack => LA's self-chain h0[s-1]->h0[s] is the pacing recurrence. LA
//   still ran v18's serial order with x-GEMM AFTER the detect. x is a pure
//   input: prefetch already flies before the spin; now the 4-tile x-compute
//   (and its load drain) also runs before the detect, off the post-detect
//   serial path. Sequence: prefetch bx -> zero acc -> x-GEMM (compiler-
//   managed waits) -> spin+barrier -> vmwait<0> (clean counted-pipe
//   baseline) -> h-stream8. Flags/stores/drains + LB path: identical v26.
//   (v9/v11 bundled this idea with confounders; this is its clean isolation
//   on the best base.)
// Prediction: LA-paced => dur 7.67 -> 6.9-7.4ms; null => both chains have
// slack, ~7.5us/step is the cross-block all-to-all recurrence floor
// (drain->flag->detect->remote-fill) — hold v27 as final.
// Ledger: clocks(v8/23) polls(v9) depth(v10/20/21) LB-order(v11/24/26)
// flaglines(v12) caching(v14) spills(v16/20/21) redundancy(v22) done;
// hop=0.6us(v13); v18 WIN -30%; v26 +0.5%.

#define Tn 1024
#define Hn 1024
#define INn 512

typedef short s8v __attribute__((ext_vector_type(8)));
typedef float f4v __attribute__((ext_vector_type(4)));
typedef unsigned short us4v __attribute__((ext_vector_type(4)));
typedef unsigned long long ull;

// ws layout (bytes)
#define WS_XB  0u           // x bf16 [64][1024][512]            = 67,108,864
#define WS_H0R 67108864u    // ring [512][ktile64][b64][16] bf16 = 67,108,864
#define WS_H1R 134217728u   // ring [256][ktile64][b64][16] bf16 = 33,554,432
#define WS_MB  167772160u   // mailbox [8][64][64] int           =    131,072

__device__ __forceinline__ unsigned short f2bf(float f) {
  unsigned int u = __float_as_uint(f);
  u += 0x7fffu + ((u >> 16) & 1u);
  return (unsigned short)(u >> 16);
}

__device__ __forceinline__ s8v pack8(const float* p) {
  float4 a = *(const float4*)p;
  float4 b = *(const float4*)(p + 4);
  s8v r;
  r[0] = (short)f2bf(a.x); r[1] = (short)f2bf(a.y);
  r[2] = (short)f2bf(a.z); r[3] = (short)f2bf(a.w);
  r[4] = (short)f2bf(b.x); r[5] = (short)f2bf(b.y);
  r[6] = (short)f2bf(b.z); r[7] = (short)f2bf(b.w);
  return r;
}

// producer store: relaxed agent-scope 8B atomic = write-through to MALL (v3+)
__device__ __forceinline__ void st8c(unsigned short* p, us4v v) {
  union { us4v v; ull u; } c; c.v = v;
  __hip_atomic_store((ull*)p, c.u, __ATOMIC_RELAXED, __HIP_MEMORY_SCOPE_AGENT);
}

// nt store via asm: ordered against other asm/memory ops (drain-count safety)
__device__ __forceinline__ void stnt16(float* p, f4v v) {
  asm volatile("global_store_dwordx4 %0, %1, off nt" :: "v"(p), "v"(v) : "memory");
}

// consumer loads: plain cached (v14). base = ktile16 base of this wave's
// K-slice (LA: w*16; LB role-split: half*32).
__device__ __forceinline__ void issue4c(s8v* f, const unsigned short* src,
                                        int base, int kt, int rl, int kg) {
#pragma unroll
  for (int m = 0; m < 4; ++m) {
    const unsigned short* p = src + (size_t)(base + kt * 2 + (kg >> 1)) * 1024
                              + (m * 16 + rl) * 16 + (kg & 1) * 8;
    asm volatile("global_load_dwordx4 %0, %1, off"
                 : "=v"(f[m]) : "v"(p) : "memory");
  }
}

template<int N> __device__ __forceinline__ void vmwait() {
  asm volatile("s_waitcnt vmcnt(%0)" :: "i"(N) : "memory");
  __builtin_amdgcn_sched_barrier(0);
}

__device__ __forceinline__ void mfma3(f4v (*acc)[4], s8v w0, s8v w1, s8v w2,
                                      const s8v f[4], const int gl) {
#pragma unroll
  for (int m = 0; m < 4; ++m) {
    acc[m][0]  = __builtin_amdgcn_mfma_f32_16x16x32_bf16(w0, f[m], acc[m][0], 0, 0, 0);
    acc[m][1]  = __builtin_amdgcn_mfma_f32_16x16x32_bf16(w1, f[m], acc[m][1], 0, 0, 0);
    acc[m][gl] = __builtin_amdgcn_mfma_f32_16x16x32_bf16(w2, f[m], acc[m][gl], 0, 0, 0);
  }
}

// v10/v18-proven deep stream, 8 tiles (LA h-stream): depth-6 ring,
// descending counted vmcnt. vmcnt==0 on entry; self-drains on exit.
template<int GL>
__device__ __forceinline__ void stream8(f4v (*acc)[4], const s8v (*wgt)[8],
    const unsigned short* src, int base, int rl, int kg) {
  s8v f[6][4];
#pragma unroll
  for (int kt = 0; kt < 6; ++kt) issue4c(f[kt], src, base, kt, rl, kg);
  vmwait<20>(); mfma3(acc, wgt[0][0], wgt[1][0], wgt[2][0], f[0], GL);
  issue4c(f[0], src, base, 6, rl, kg);
  vmwait<20>(); mfma3(acc, wgt[0][1], wgt[1][1], wgt[2][1], f[1], GL);
  issue4c(f[1], src, base, 7, rl, kg);
  vmwait<20>(); mfma3(acc, wgt[0][2], wgt[1][2], wgt[2][2], f[2], GL);
  vmwait<16>(); mfma3(acc, wgt[0][3], wgt[1][3], wgt[2][3], f[3], GL);
  vmwait<12>(); mfma3(acc, wgt[0][4], wgt[1][4], wgt[2][4], f[4], GL);
  vmwait<8>();  mfma3(acc, wgt[0][5], wgt[1][5], wgt[2][5], f[5], GL);
  vmwait<4>();  mfma3(acc, wgt[0][6], wgt[1][6], wgt[2][6], f[0], GL);
  vmwait<0>();  mfma3(acc, wgt[0][7], wgt[1][7], wgt[2][7], f[1], GL);
}

// v26 role-split stream, 16 tiles (K=512 of one LB GEMM): same depth-6
// counted-vmcnt discipline. vmcnt==0 on entry; self-drains on exit.
template<int GL>
__device__ __forceinline__ void stream16(f4v (*acc)[4], const s8v (*wgt)[16],
    const unsigned short* src, int base, int rl, int kg) {
  s8v f[6][4];
#pragma unroll
  for (int kt = 0; kt < 6; ++kt) issue4c(f[kt], src, base, kt, rl, kg);
  vmwait<20>(); mfma3(acc, wgt[0][0],  wgt[1][0],  wgt[2][0],  f[0], GL); issue4c(f[0], src, base, 6,  rl, kg);
  vmwait<20>(); mfma3(acc, wgt[0][1],  wgt[1][1],  wgt[2][1],  f[1], GL); issue4c(f[1], src, base, 7,  rl, kg);
  vmwait<20>(); mfma3(acc, wgt[0][2],  wgt[1][2],  wgt[2][2],  f[2], GL); issue4c(f[2], src, base, 8,  rl, kg);
  vmwait<20>(); mfma3(acc, wgt[0][3],  wgt[1][3],  wgt[2][3],  f[3], GL); issue4c(f[3], src, base, 9,  rl, kg);
  vmwait<20>(); mfma3(acc, wgt[0][4],  wgt[1][4],  wgt[2][4],  f[4], GL); issue4c(f[4], src, base, 10, rl, kg);
  vmwait<20>(); mfma3(acc, wgt[0][5],  wgt[1][5],  wgt[2][5],  f[5], GL); issue4c(f[5], src, base, 11, rl, kg);
  vmwait<20>(); mfma3(acc, wgt[0][6],  wgt[1][6],  wgt[2][6],  f[0], GL); issue4c(f[0], src, base, 12, rl, kg);
  vmwait<20>(); mfma3(acc, wgt[0][7],  wgt[1][7],  wgt[2][7],  f[1], GL); issue4c(f[1], src, base, 13, rl, kg);
  vmwait<20>(); mfma3(acc, wgt[0][8],  wgt[1][8],  wgt[2][8],  f[2], GL); issue4c(f[2], src, base, 14, rl, kg);
  vmwait<20>(); mfma3(acc, wgt[0][9],  wgt[1][9],  wgt[2][9],  f[3], GL); issue4c(f[3], src, base, 15, rl, kg);
  vmwait<20>(); mfma3(acc, wgt[0][10], wgt[1][10], wgt[2][10], f[4], GL);
  vmwait<16>(); mfma3(acc, wgt[0][11], wgt[1][11], wgt[2][11], f[5], GL);
  vmwait<12>(); mfma3(acc, wgt[0][12], wgt[1][12], wgt[2][12], f[0], GL);
  vmwait<8>();  mfma3(acc, wgt[0][13], wgt[1][13], wgt[2][13], f[1], GL);
  vmwait<4>();  mfma3(acc, wgt[0][14], wgt[1][14], wgt[2][14], f[2], GL);
  vmwait<0>();  mfma3(acc, wgt[0][15], wgt[1][15], wgt[2][15], f[3], GL);
}

__global__ void cvt_bf16_kernel(const float* __restrict__ src,
                                unsigned short* __restrict__ dst, int n4) {
  int i = blockIdx.x * blockDim.x + threadIdx.x;
  int st = gridDim.x * blockDim.x;
  for (; i < n4; i += st) {
    const float4 v = *(const float4*)(src + 4 * (size_t)i);
    us4v o;
    o[0] = f2bf(v.x); o[1] = f2bf(v.y); o[2] = f2bf(v.z); o[3] = f2bf(v.w);
    *(us4v*)(dst + 4 * (size_t)i) = o;
  }
}

__global__ void init_all(const float* __restrict__ h0in, char* __restrict__ ws) {
  int i = blockIdx.x * blockDim.x + threadIdx.x;   // grid 528*256 = 135168
  unsigned short* h0r = (unsigned short*)(ws + WS_H0R);
  unsigned short* h1r = (unsigned short*)(ws + WS_H1R);
  int* MB = (int*)(ws + WS_MB);
  if (i < 65536) {
    int b = i >> 10, h = i & 1023;
    int off = (h >> 4) * 1024 + b * 16 + (h & 15);
    h0r[511 * 65536 + off] = f2bf(h0in[i]);          // slot for step -1
    h1r[255 * 65536 + off] = f2bf(h0in[65536 + i]);  // slot for step -1
  }
  if (i < 32768) MB[i] = 0;                          // all mailbox groups: 0
}

// consumer wait: 64-lane gather over this block's PRIVATE mailbox rows.
// row index = grp*64 + consumer; lane = producer. Safe for 1-2 reader waves.
__device__ __forceinline__ void mb_wait(const int* MB, int r1, int t1,
                                        int r2, int t2, int lane) {
  const int* p1 = MB + (r1 * 64 + lane);
  const int* p2 = MB + (r2 * 64 + lane);
  int tries = 0;
  for (;;) {
    int v1 = __hip_atomic_load(p1, __ATOMIC_RELAXED, __HIP_MEMORY_SCOPE_AGENT);
    int v2 = __hip_atomic_load(p2, __ATOMIC_RELAXED, __HIP_MEMORY_SCOPE_AGENT);
    if (__all(v1 >= t1 && v2 >= t2)) return;
    __builtin_amdgcn_s_sleep(1);
    if (++tries > (1 << 22)) return;   // fail visibly, never hang
  }
}

__global__ __launch_bounds__(256)
__attribute__((amdgpu_waves_per_eu(1, 1)))   // 1 wave/EU: full unified RF
void gru_persist(
    const float* __restrict__ h0in,
    const float* __restrict__ wih0, const float* __restrict__ whh0,
    const float* __restrict__ bih0, const float* __restrict__ bhh0,
    const float* __restrict__ wih1, const float* __restrict__ whh1,
    const float* __restrict__ bih1, const float* __restrict__ bhh1,
    float* __restrict__ out, char* __restrict__ ws)
{
  const unsigned short* xb = (const unsigned short*)(ws + WS_XB);
  unsigned short* h0r = (unsigned short*)(ws + WS_H0R);
  unsigned short* h1r = (unsigned short*)(ws + WS_H1R);
  int* MB = (int*)(ws + WS_MB);

  const int blk = blockIdx.x;
  const int tid = threadIdx.x;

  if (blk >= 128) {
    // busy-clock pad (v18 config, measured-best variant kept unchanged)
    const int c = blk & 63;
    float a0 = 1.0f + (float)tid * 1e-6f, a1 = a0 + 0.25f;
    float a2 = a0 + 0.5f, a3 = a0 + 0.75f;
    const float mm = 0.99999988f, cc = 1e-7f;
    int run = 1;
    for (int it = 0; it < (1 << 17) && run; ++it) {
#pragma unroll
      for (int u = 0; u < 256; ++u) {
        a0 = __builtin_fmaf(a0, mm, cc); a1 = __builtin_fmaf(a1, mm, cc);
        a2 = __builtin_fmaf(a2, mm, cc); a3 = __builtin_fmaf(a3, mm, cc);
      }
      if ((it & 15) == 0) {
        int v = __hip_atomic_load(MB + (((2 * 64) + c) * 64 + (tid & 63)),
                                  __ATOMIC_RELAXED, __HIP_MEMORY_SCOPE_AGENT);
        if (__all(v >= Tn)) run = 0;
      }
    }
    asm volatile("" :: "v"(a0), "v"(a1), "v"(a2), "v"(a3));  // keep chains live
    return;
  }

  const bool isA = blk < 64;
  const int jt = blk & 63, jj = jt * 16;
  const int w = tid >> 6;                    // wave index
  const int lane = tid & 63;
  const int rl = lane & 15, kg = lane >> 4;

  __shared__ float cmb[4][4][64][20];        // stride 80B: conflict-free (r6)

  const int b = w * 16 + rl;                 // owner batch rows (epilogue)
  const int j0 = jj + kg * 4;                // owner j base (epilogue)

  const float* bi = isA ? bih0 : bih1;
  const float* bh = isA ? bhh0 : bhh1;
  const f4v bir = *(const f4v*)(bi + j0),        bhr = *(const f4v*)(bh + j0);
  const f4v biz = *(const f4v*)(bi + 1024 + j0), bhz = *(const f4v*)(bh + 1024 + j0);
  const f4v bin = *(const f4v*)(bi + 2048 + j0), bhn = *(const f4v*)(bh + 2048 + j0);

  // register-resident fp32 hidden state (this thread's (b, j0..j0+3))
  f4v hv = *(const f4v*)(h0in + (isA ? 0u : 65536u) + (size_t)b * Hn + j0);

  if (isA) {
    // ========== LA: v18 path + v27 x-GEMM hoist before the detect ==========
    s8v wx[3][4], wh_[3][8];
#pragma unroll
    for (int g = 0; g < 3; ++g) {
#pragma unroll
      for (int kt = 0; kt < 4; ++kt)
        wx[g][kt] = pack8(wih0 + (size_t)(g * 1024 + jj + rl) * INn + w * 128 + kt * 32 + kg * 8);
#pragma unroll
      for (int kt = 0; kt < 8; ++kt)
        wh_[g][kt] = pack8(whh0 + (size_t)(g * 1024 + jj + rl) * Hn + w * 256 + kt * 32 + kg * 8);
    }

    for (int s = 0; s < Tn; ++s) {
      // x prefetch (plain cached loads; compiler inserts the waits)
      s8v bx[4][4];
#pragma unroll
      for (int m = 0; m < 4; ++m)
#pragma unroll
        for (int kt = 0; kt < 4; ++kt)
          bx[m][kt] = *(const s8v*)(xb + ((size_t)(m * 16 + rl) * Tn + s) * INn + w * 128 + kt * 32 + kg * 8);

      f4v acc[4][4];
#pragma unroll
      for (int m = 0; m < 4; ++m)
#pragma unroll
        for (int g = 0; g < 4; ++g) acc[m][g] = (f4v){0.f, 0.f, 0.f, 0.f};

      // v27: x-GEMM BEFORE the detect — pure-input work overlaps the wait
#pragma unroll
      for (int kt = 0; kt < 4; ++kt) {
        s8v f4[4] = { bx[0][kt], bx[1][kt], bx[2][kt], bx[3][kt] };
        mfma3(acc, wx[0][kt], wx[1][kt], wx[2][kt], f4, 2);
      }

      if (w == 0) mb_wait(MB, 0 * 64 + jt, s, 3 * 64 + jt, s - 255, lane);
      __syncthreads();
      vmwait<0>();                           // clean baseline for counted pipe

      const unsigned short* hsrc = h0r + (size_t)((s - 1) & 511) * 65536;
      stream8<3>(acc, wh_, hsrc, w * 16, rl, kg);

      // cross-wave K-combine
#pragma unroll
      for (int d = 0; d < 4; ++d) if (d != w)
#pragma unroll
        for (int g = 0; g < 4; ++g) *(f4v*)&cmb[d][w][lane][g * 4] = acc[d][g];
      __syncthreads();
      f4v hsum[4];
#pragma unroll
      for (int g = 0; g < 4; ++g) {
        hsum[g] = acc[w][g];
#pragma unroll
        for (int src = 0; src < 4; ++src) if (src != w) hsum[g] += *(f4v*)&cmb[w][src][lane][g * 4];
      }

      us4v hb4;
#pragma unroll
      for (int rr = 0; rr < 4; ++rr) {
        float hp = hv[rr];
        float rg = 1.f / (1.f + __expf(-(hsum[0][rr] + bir[rr] + bhr[rr])));
        float zg = 1.f / (1.f + __expf(-(hsum[1][rr] + biz[rr] + bhz[rr])));
        float narg = hsum[2][rr] + bin[rr] + rg * (hsum[3][rr] + bhn[rr]);
        float e2 = __expf(2.f * narg);
        float ng = 1.f - 2.f / (e2 + 1.f);
        float nv = (1.f - zg) * ng + zg * hp;
        hv[rr] = 0.1f * hp + 0.9f * nv;
      }
      hb4[0] = f2bf(hv[0]); hb4[1] = f2bf(hv[1]); hb4[2] = f2bf(hv[2]); hb4[3] = f2bf(hv[3]);

      st8c(h0r + (size_t)(s & 511) * 65536 + jt * 1024 + b * 16 + kg * 4, hb4);
      if (s == Tn - 1)
        stnt16(out + 67108864u + (size_t)b * Hn + j0, hv);
      vmwait<0>();
      __syncthreads();
      if (tid < 64) {
        __hip_atomic_store(MB + ((0 * 64 + tid) * 64 + jt), s + 1,
                           __ATOMIC_RELAXED, __HIP_MEMORY_SCOPE_AGENT);
        __hip_atomic_store(MB + ((1 * 64 + tid) * 64 + jt), s + 1,
                           __ATOMIC_RELAXED, __HIP_MEMORY_SCOPE_AGENT);
      }
    }
  } else {
    // ================= LB: v26 wave role-split (unchanged) =================
    const int role = w >> 1;                 // 0 = a-GEMM, 1 = h-GEMM
    const int half = w & 1;                  // K half (512 wide)
    const float* Wsrc = role ? whh1 : wih1;
    s8v wgt[3][16];
#pragma unroll
    for (int g = 0; g < 3; ++g)
#pragma unroll
      for (int kt = 0; kt < 16; ++kt)
        wgt[g][kt] = pack8(Wsrc + (size_t)(g * 1024 + jj + rl) * Hn + half * 512 + kt * 32 + kg * 8);

    for (int s = 0; s < Tn; ++s) {
      f4v acc[4][4];
#pragma unroll
      for (int m = 0; m < 4; ++m)
#pragma unroll
        for (int g = 0; g < 4; ++g) acc[m][g] = (f4v){0.f, 0.f, 0.f, 0.f};

      const unsigned short* hsrc = h1r + (size_t)((s - 1) & 255) * 65536;
      const unsigned short* asrc = h0r + (size_t)(s & 511) * 65536;

      if (role == 0) {
        // a-waves: gate on CA[s] (LA ~255 ahead => first-poll hit)
        mb_wait(MB, 1 * 64 + jt, s + 1, 1 * 64 + jt, s + 1, lane);
        vmwait<0>();
        stream16<2>(acc, wgt, asrc, half * 32, rl, kg);
      } else {
        // h-waves: self-gate on CB[s-1], then the critical h-GEMM
        mb_wait(MB, 2 * 64 + jt, s, 2 * 64 + jt, s, lane);
        vmwait<0>();
        stream16<3>(acc, wgt, hsrc, half * 32, rl, kg);
      }

      // cross-wave K-combine (sums a-partials + h-partials)
#pragma unroll
      for (int d = 0; d < 4; ++d) if (d != w)
#pragma unroll
        for (int g = 0; g < 4; ++g) *(f4v*)&cmb[d][w][lane][g * 4] = acc[d][g];
      __syncthreads();
      f4v hsum[4];
#pragma unroll
      for (int g = 0; g < 4; ++g) {
        hsum[g] = acc[w][g];
#pragma unroll
        for (int src = 0; src < 4; ++src) if (src != w) hsum[g] += *(f4v*)&cmb[w][src][lane][g * 4];
      }

      us4v hb4;
#pragma unroll
      for (int rr = 0; rr < 4; ++rr) {
        float hp = hv[rr];
        float rg = 1.f / (1.f + __expf(-(hsum[0][rr] + bir[rr] + bhr[rr])));
        float zg = 1.f / (1.f + __expf(-(hsum[1][rr] + biz[rr] + bhz[rr])));
        float narg = hsum[2][rr] + bin[rr] + rg * (hsum[3][rr] + bhn[rr]);
        float e2 = __expf(2.f * narg);
        float ng = 1.f - 2.f / (e2 + 1.f);
        float nv = (1.f - zg) * ng + zg * hp;
        hv[rr] = 0.1f * hp + 0.9f * nv;
      }
      hb4[0] = f2bf(hv[0]); hb4[1] = f2bf(hv[1]); hb4[2] = f2bf(hv[2]); hb4[3] = f2bf(hv[3]);

      st8c(h1r + (size_t)(s & 255) * 65536 + jt * 1024 + b * 16 + kg * 4, hb4);
      stnt16(out + ((size_t)b * Tn + s) * Hn + j0, hv);
      if (s == Tn - 1) {
        stnt16(out + 67108864u + 65536u + (size_t)b * Hn + j0, hv);
        vmwait<0>();
      } else {
        vmwait<1>();                         // st8c acked; out-store off-chain
      }
      __syncthreads();
      if (tid < 64) {
        __hip_atomic_store(MB + ((2 * 64 + tid) * 64 + jt), s + 1,
                           __ATOMIC_RELAXED, __HIP_MEMORY_SCOPE_AGENT);
        __hip_atomic_store(MB + ((3 * 64 + tid) * 64 + jt), s + 1,
                           __ATOMIC_RELAXED, __HIP_MEMORY_SCOPE_AGENT);
      }
    }
  }
}

extern "C" void kernel_launch(void* const* d_in, const int* in_sizes, int n_in,
                              void* d_out, int out_size, void* d_ws, size_t ws_size,
                              hipStream_t stream) {
  (void)in_sizes; (void)n_in; (void)out_size; (void)ws_size;
  const float* x    = (const float*)d_in[0];
  const float* h0in = (const float*)d_in[1];
  const float* wih0 = (const float*)d_in[2];
  const float* whh0 = (const float*)d_in[3];
  const float* bih0 = (const float*)d_in[4];
  const float* bhh0 = (const float*)d_in[5];
  const float* wih1 = (const float*)d_in[6];
  const float* whh1 = (const float*)d_in[7];
  const float* bih1 = (const float*)d_in[8];
  const float* bhh1 = (const float*)d_in[9];
  float* out = (float*)d_out;
  char* ws = (char*)d_ws;

  cvt_bf16_kernel<<<2048, 256, 0, stream>>>(x, (unsigned short*)(ws + WS_XB), 33554432 / 4);
  init_all<<<528, 256, 0, stream>>>(h0in, ws);
  gru_persist<<<dim3(256), dim3(256), 0, stream>>>(
      h0in, wih0, whh0, bih0, bhh0, wih1, whh1, bih1, bhh1, out, ws);
}

// Round 21
// 7671.806 us; speedup vs baseline: 1.1930x; 1.1930x over previous
//
#include <hip/hip_runtime.h>

// ZoneoutGRU persistent kernel v28 = v26 byte-exact (session best: 7,674 us,
// -30% vs session-start 11,032). B=64, T=1024, IN=512, H=1024, L=2, zo=0.1.
// 128 active blocks (64 LA, 64 LB), 256 thr. Mailbox sync (v12), plain
// cached stream loads (v14), waves_per_eu(1,1) (v16), rule-#20 weight fix
// (v18, -24%), LB wave role-split (v26).
// v27 (LA x-GEMM hoist) REVERTED: it delayed wave0's poll issue ~1us/step —
// on the pacing chain the detect's issue time IS the critical event; every
// hoist-ahead-of-spin attempt regressed (v9/v11/v24/v27).
// Final ledger: clocks(v8/23) polls(v9) depth(v10/20/21) order(v11/24/27)
// flaglines(v12) caching(v14) spills(v16/20/21) redundancy(v22, MSHR-merged)
// exonerated; sync-hop 0.6us (v13). Residual ~7.4us/step = cross-block
// recurrence latency floor (store-drain -> flag -> detect -> remote fill),
// invariant to every tested in-structure knob.

#define Tn 1024
#define Hn 1024
#define INn 512

typedef short s8v __attribute__((ext_vector_type(8)));
typedef float f4v __attribute__((ext_vector_type(4)));
typedef unsigned short us4v __attribute__((ext_vector_type(4)));
typedef unsigned long long ull;

// ws layout (bytes)
#define WS_XB  0u           // x bf16 [64][1024][512]            = 67,108,864
#define WS_H0R 67108864u    // ring [512][ktile64][b64][16] bf16 = 67,108,864
#define WS_H1R 134217728u   // ring [256][ktile64][b64][16] bf16 = 33,554,432
#define WS_MB  167772160u   // mailbox [8][64][64] int           =    131,072

__device__ __forceinline__ unsigned short f2bf(float f) {
  unsigned int u = __float_as_uint(f);
  u += 0x7fffu + ((u >> 16) & 1u);
  return (unsigned short)(u >> 16);
}

__device__ __forceinline__ s8v pack8(const float* p) {
  float4 a = *(const float4*)p;
  float4 b = *(const float4*)(p + 4);
  s8v r;
  r[0] = (short)f2bf(a.x); r[1] = (short)f2bf(a.y);
  r[2] = (short)f2bf(a.z); r[3] = (short)f2bf(a.w);
  r[4] = (short)f2bf(b.x); r[5] = (short)f2bf(b.y);
  r[6] = (short)f2bf(b.z); r[7] = (short)f2bf(b.w);
  return r;
}

// producer store: relaxed agent-scope 8B atomic = write-through to MALL (v3+)
__device__ __forceinline__ void st8c(unsigned short* p, us4v v) {
  union { us4v v; ull u; } c; c.v = v;
  __hip_atomic_store((ull*)p, c.u, __ATOMIC_RELAXED, __HIP_MEMORY_SCOPE_AGENT);
}

// nt store via asm: ordered against other asm/memory ops (drain-count safety)
__device__ __forceinline__ void stnt16(float* p, f4v v) {
  asm volatile("global_store_dwordx4 %0, %1, off nt" :: "v"(p), "v"(v) : "memory");
}

// consumer loads: plain cached (v14). base = ktile16 base of this wave's
// K-slice (LA: w*16; LB role-split: half*32).
__device__ __forceinline__ void issue4c(s8v* f, const unsigned short* src,
                                        int base, int kt, int rl, int kg) {
#pragma unroll
  for (int m = 0; m < 4; ++m) {
    const unsigned short* p = src + (size_t)(base + kt * 2 + (kg >> 1)) * 1024
                              + (m * 16 + rl) * 16 + (kg & 1) * 8;
    asm volatile("global_load_dwordx4 %0, %1, off"
                 : "=v"(f[m]) : "v"(p) : "memory");
  }
}

template<int N> __device__ __forceinline__ void vmwait() {
  asm volatile("s_waitcnt vmcnt(%0)" :: "i"(N) : "memory");
  __builtin_amdgcn_sched_barrier(0);
}

__device__ __forceinline__ void mfma3(f4v (*acc)[4], s8v w0, s8v w1, s8v w2,
                                      const s8v f[4], const int gl) {
#pragma unroll
  for (int m = 0; m < 4; ++m) {
    acc[m][0]  = __builtin_amdgcn_mfma_f32_16x16x32_bf16(w0, f[m], acc[m][0], 0, 0, 0);
    acc[m][1]  = __builtin_amdgcn_mfma_f32_16x16x32_bf16(w1, f[m], acc[m][1], 0, 0, 0);
    acc[m][gl] = __builtin_amdgcn_mfma_f32_16x16x32_bf16(w2, f[m], acc[m][gl], 0, 0, 0);
  }
}

// v10/v18-proven deep stream, 8 tiles (LA h-stream): depth-6 ring,
// descending counted vmcnt. vmcnt==0 on entry; self-drains on exit.
template<int GL>
__device__ __forceinline__ void stream8(f4v (*acc)[4], const s8v (*wgt)[8],
    const unsigned short* src, int base, int rl, int kg) {
  s8v f[6][4];
#pragma unroll
  for (int kt = 0; kt < 6; ++kt) issue4c(f[kt], src, base, kt, rl, kg);
  vmwait<20>(); mfma3(acc, wgt[0][0], wgt[1][0], wgt[2][0], f[0], GL);
  issue4c(f[0], src, base, 6, rl, kg);
  vmwait<20>(); mfma3(acc, wgt[0][1], wgt[1][1], wgt[2][1], f[1], GL);
  issue4c(f[1], src, base, 7, rl, kg);
  vmwait<20>(); mfma3(acc, wgt[0][2], wgt[1][2], wgt[2][2], f[2], GL);
  vmwait<16>(); mfma3(acc, wgt[0][3], wgt[1][3], wgt[2][3], f[3], GL);
  vmwait<12>(); mfma3(acc, wgt[0][4], wgt[1][4], wgt[2][4], f[4], GL);
  vmwait<8>();  mfma3(acc, wgt[0][5], wgt[1][5], wgt[2][5], f[5], GL);
  vmwait<4>();  mfma3(acc, wgt[0][6], wgt[1][6], wgt[2][6], f[0], GL);
  vmwait<0>();  mfma3(acc, wgt[0][7], wgt[1][7], wgt[2][7], f[1], GL);
}

// v26 role-split stream, 16 tiles (K=512 of one LB GEMM): same depth-6
// counted-vmcnt discipline. vmcnt==0 on entry; self-drains on exit.
template<int GL>
__device__ __forceinline__ void stream16(f4v (*acc)[4], const s8v (*wgt)[16],
    const unsigned short* src, int base, int rl, int kg) {
  s8v f[6][4];
#pragma unroll
  for (int kt = 0; kt < 6; ++kt) issue4c(f[kt], src, base, kt, rl, kg);
  vmwait<20>(); mfma3(acc, wgt[0][0],  wgt[1][0],  wgt[2][0],  f[0], GL); issue4c(f[0], src, base, 6,  rl, kg);
  vmwait<20>(); mfma3(acc, wgt[0][1],  wgt[1][1],  wgt[2][1],  f[1], GL); issue4c(f[1], src, base, 7,  rl, kg);
  vmwait<20>(); mfma3(acc, wgt[0][2],  wgt[1][2],  wgt[2][2],  f[2], GL); issue4c(f[2], src, base, 8,  rl, kg);
  vmwait<20>(); mfma3(acc, wgt[0][3],  wgt[1][3],  wgt[2][3],  f[3], GL); issue4c(f[3], src, base, 9,  rl, kg);
  vmwait<20>(); mfma3(acc, wgt[0][4],  wgt[1][4],  wgt[2][4],  f[4], GL); issue4c(f[4], src, base, 10, rl, kg);
  vmwait<20>(); mfma3(acc, wgt[0][5],  wgt[1][5],  wgt[2][5],  f[5], GL); issue4c(f[5], src, base, 11, rl, kg);
  vmwait<20>(); mfma3(acc, wgt[0][6],  wgt[1][6],  wgt[2][6],  f[0], GL); issue4c(f[0], src, base, 12, rl, kg);
  vmwait<20>(); mfma3(acc, wgt[0][7],  wgt[1][7],  wgt[2][7],  f[1], GL); issue4c(f[1], src, base, 13, rl, kg);
  vmwait<20>(); mfma3(acc, wgt[0][8],  wgt[1][8],  wgt[2][8],  f[2], GL); issue4c(f[2], src, base, 14, rl, kg);
  vmwait<20>(); mfma3(acc, wgt[0][9],  wgt[1][9],  wgt[2][9],  f[3], GL); issue4c(f[3], src, base, 15, rl, kg);
  vmwait<20>(); mfma3(acc, wgt[0][10], wgt[1][10], wgt[2][10], f[4], GL);
  vmwait<16>(); mfma3(acc, wgt[0][11], wgt[1][11], wgt[2][11], f[5], GL);
  vmwait<12>(); mfma3(acc, wgt[0][12], wgt[1][12], wgt[2][12], f[0], GL);
  vmwait<8>();  mfma3(acc, wgt[0][13], wgt[1][13], wgt[2][13], f[1], GL);
  vmwait<4>();  mfma3(acc, wgt[0][14], wgt[1][14], wgt[2][14], f[2], GL);
  vmwait<0>();  mfma3(acc, wgt[0][15], wgt[1][15], wgt[2][15], f[3], GL);
}

__global__ void cvt_bf16_kernel(const float* __restrict__ src,
                                unsigned short* __restrict__ dst, int n4) {
  int i = blockIdx.x * blockDim.x + threadIdx.x;
  int st = gridDim.x * blockDim.x;
  for (; i < n4; i += st) {
    const float4 v = *(const float4*)(src + 4 * (size_t)i);
    us4v o;
    o[0] = f2bf(v.x); o[1] = f2bf(v.y); o[2] = f2bf(v.z); o[3] = f2bf(v.w);
    *(us4v*)(dst + 4 * (size_t)i) = o;
  }
}

__global__ void init_all(const float* __restrict__ h0in, char* __restrict__ ws) {
  int i = blockIdx.x * blockDim.x + threadIdx.x;   // grid 528*256 = 135168
  unsigned short* h0r = (unsigned short*)(ws + WS_H0R);
  unsigned short* h1r = (unsigned short*)(ws + WS_H1R);
  int* MB = (int*)(ws + WS_MB);
  if (i < 65536) {
    int b = i >> 10, h = i & 1023;
    int off = (h >> 4) * 1024 + b * 16 + (h & 15);
    h0r[511 * 65536 + off] = f2bf(h0in[i]);          // slot for step -1
    h1r[255 * 65536 + off] = f2bf(h0in[65536 + i]);  // slot for step -1
  }
  if (i < 32768) MB[i] = 0;                          // all mailbox groups: 0
}

// consumer wait: 64-lane gather over this block's PRIVATE mailbox rows.
// row index = grp*64 + consumer; lane = producer. Safe for 1-2 reader waves.
__device__ __forceinline__ void mb_wait(const int* MB, int r1, int t1,
                                        int r2, int t2, int lane) {
  const int* p1 = MB + (r1 * 64 + lane);
  const int* p2 = MB + (r2 * 64 + lane);
  int tries = 0;
  for (;;) {
    int v1 = __hip_atomic_load(p1, __ATOMIC_RELAXED, __HIP_MEMORY_SCOPE_AGENT);
    int v2 = __hip_atomic_load(p2, __ATOMIC_RELAXED, __HIP_MEMORY_SCOPE_AGENT);
    if (__all(v1 >= t1 && v2 >= t2)) return;
    __builtin_amdgcn_s_sleep(1);
    if (++tries > (1 << 22)) return;   // fail visibly, never hang
  }
}

__global__ __launch_bounds__(256)
__attribute__((amdgpu_waves_per_eu(1, 1)))   // 1 wave/EU: full unified RF
void gru_persist(
    const float* __restrict__ h0in,
    const float* __restrict__ wih0, const float* __restrict__ whh0,
    const float* __restrict__ bih0, const float* __restrict__ bhh0,
    const float* __restrict__ wih1, const float* __restrict__ whh1,
    const float* __restrict__ bih1, const float* __restrict__ bhh1,
    float* __restrict__ out, char* __restrict__ ws)
{
  const unsigned short* xb = (const unsigned short*)(ws + WS_XB);
  unsigned short* h0r = (unsigned short*)(ws + WS_H0R);
  unsigned short* h1r = (unsigned short*)(ws + WS_H1R);
  int* MB = (int*)(ws + WS_MB);

  const int blk = blockIdx.x;
  const int tid = threadIdx.x;

  if (blk >= 128) {
    // busy-clock pad (v18 config, measured-best variant kept unchanged)
    const int c = blk & 63;
    float a0 = 1.0f + (float)tid * 1e-6f, a1 = a0 + 0.25f;
    float a2 = a0 + 0.5f, a3 = a0 + 0.75f;
    const float mm = 0.99999988f, cc = 1e-7f;
    int run = 1;
    for (int it = 0; it < (1 << 17) && run; ++it) {
#pragma unroll
      for (int u = 0; u < 256; ++u) {
        a0 = __builtin_fmaf(a0, mm, cc); a1 = __builtin_fmaf(a1, mm, cc);
        a2 = __builtin_fmaf(a2, mm, cc); a3 = __builtin_fmaf(a3, mm, cc);
      }
      if ((it & 15) == 0) {
        int v = __hip_atomic_load(MB + (((2 * 64) + c) * 64 + (tid & 63)),
                                  __ATOMIC_RELAXED, __HIP_MEMORY_SCOPE_AGENT);
        if (__all(v >= Tn)) run = 0;
      }
    }
    asm volatile("" :: "v"(a0), "v"(a1), "v"(a2), "v"(a3));  // keep chains live
    return;
  }

  const bool isA = blk < 64;
  const int jt = blk & 63, jj = jt * 16;
  const int w = tid >> 6;                    // wave index
  const int lane = tid & 63;
  const int rl = lane & 15, kg = lane >> 4;

  __shared__ float cmb[4][4][64][20];        // stride 80B: conflict-free (r6)

  const int b = w * 16 + rl;                 // owner batch rows (epilogue)
  const int j0 = jj + kg * 4;                // owner j base (epilogue)

  const float* bi = isA ? bih0 : bih1;
  const float* bh = isA ? bhh0 : bhh1;
  const f4v bir = *(const f4v*)(bi + j0),        bhr = *(const f4v*)(bh + j0);
  const f4v biz = *(const f4v*)(bi + 1024 + j0), bhz = *(const f4v*)(bh + 1024 + j0);
  const f4v bin = *(const f4v*)(bi + 2048 + j0), bhn = *(const f4v*)(bh + 2048 + j0);

  // register-resident fp32 hidden state (this thread's (b, j0..j0+3))
  f4v hv = *(const f4v*)(h0in + (isA ? 0u : 65536u) + (size_t)b * Hn + j0);

  if (isA) {
    // ===================== LA: v18 path, unchanged =====================
    s8v wx[3][4], wh_[3][8];
#pragma unroll
    for (int g = 0; g < 3; ++g) {
#pragma unroll
      for (int kt = 0; kt < 4; ++kt)
        wx[g][kt] = pack8(wih0 + (size_t)(g * 1024 + jj + rl) * INn + w * 128 + kt * 32 + kg * 8);
#pragma unroll
      for (int kt = 0; kt < 8; ++kt)
        wh_[g][kt] = pack8(whh0 + (size_t)(g * 1024 + jj + rl) * Hn + w * 256 + kt * 32 + kg * 8);
    }

    for (int s = 0; s < Tn; ++s) {
      // x prefetch (plain cached loads) before spin
      s8v bx[4][4];
#pragma unroll
      for (int m = 0; m < 4; ++m)
#pragma unroll
        for (int kt = 0; kt < 4; ++kt)
          bx[m][kt] = *(const s8v*)(xb + ((size_t)(m * 16 + rl) * Tn + s) * INn + w * 128 + kt * 32 + kg * 8);
      if (w == 0) mb_wait(MB, 0 * 64 + jt, s, 3 * 64 + jt, s - 255, lane);
      __syncthreads();
      vmwait<0>();

      f4v acc[4][4];
#pragma unroll
      for (int m = 0; m < 4; ++m)
#pragma unroll
        for (int g = 0; g < 4; ++g) acc[m][g] = (f4v){0.f, 0.f, 0.f, 0.f};

      const unsigned short* hsrc = h0r + (size_t)((s - 1) & 511) * 65536;
#pragma unroll
      for (int kt = 0; kt < 4; ++kt) {
        s8v f4[4] = { bx[0][kt], bx[1][kt], bx[2][kt], bx[3][kt] };
        mfma3(acc, wx[0][kt], wx[1][kt], wx[2][kt], f4, 2);
      }
      stream8<3>(acc, wh_, hsrc, w * 16, rl, kg);

      // cross-wave K-combine
#pragma unroll
      for (int d = 0; d < 4; ++d) if (d != w)
#pragma unroll
        for (int g = 0; g < 4; ++g) *(f4v*)&cmb[d][w][lane][g * 4] = acc[d][g];
      __syncthreads();
      f4v hsum[4];
#pragma unroll
      for (int g = 0; g < 4; ++g) {
        hsum[g] = acc[w][g];
#pragma unroll
        for (int src = 0; src < 4; ++src) if (src != w) hsum[g] += *(f4v*)&cmb[w][src][lane][g * 4];
      }

      us4v hb4;
#pragma unroll
      for (int rr = 0; rr < 4; ++rr) {
        float hp = hv[rr];
        float rg = 1.f / (1.f + __expf(-(hsum[0][rr] + bir[rr] + bhr[rr])));
        float zg = 1.f / (1.f + __expf(-(hsum[1][rr] + biz[rr] + bhz[rr])));
        float narg = hsum[2][rr] + bin[rr] + rg * (hsum[3][rr] + bhn[rr]);
        float e2 = __expf(2.f * narg);
        float ng = 1.f - 2.f / (e2 + 1.f);
        float nv = (1.f - zg) * ng + zg * hp;
        hv[rr] = 0.1f * hp + 0.9f * nv;
      }
      hb4[0] = f2bf(hv[0]); hb4[1] = f2bf(hv[1]); hb4[2] = f2bf(hv[2]); hb4[3] = f2bf(hv[3]);

      st8c(h0r + (size_t)(s & 511) * 65536 + jt * 1024 + b * 16 + kg * 4, hb4);
      if (s == Tn - 1)
        stnt16(out + 67108864u + (size_t)b * Hn + j0, hv);
      vmwait<0>();
      __syncthreads();
      if (tid < 64) {
        __hip_atomic_store(MB + ((0 * 64 + tid) * 64 + jt), s + 1,
                           __ATOMIC_RELAXED, __HIP_MEMORY_SCOPE_AGENT);
        __hip_atomic_store(MB + ((1 * 64 + tid) * 64 + jt), s + 1,
                           __ATOMIC_RELAXED, __HIP_MEMORY_SCOPE_AGENT);
      }
    }
  } else {
    // ================= LB: v26 wave role-split =================
    const int role = w >> 1;                 // 0 = a-GEMM, 1 = h-GEMM
    const int half = w & 1;                  // K half (512 wide)
    const float* Wsrc = role ? whh1 : wih1;
    s8v wgt[3][16];
#pragma unroll
    for (int g = 0; g < 3; ++g)
#pragma unroll
      for (int kt = 0; kt < 16; ++kt)
        wgt[g][kt] = pack8(Wsrc + (size_t)(g * 1024 + jj + rl) * Hn + half * 512 + kt * 32 + kg * 8);

    for (int s = 0; s < Tn; ++s) {
      f4v acc[4][4];
#pragma unroll
      for (int m = 0; m < 4; ++m)
#pragma unroll
        for (int g = 0; g < 4; ++g) acc[m][g] = (f4v){0.f, 0.f, 0.f, 0.f};

      const unsigned short* hsrc = h1r + (size_t)((s - 1) & 255) * 65536;
      const unsigned short* asrc = h0r + (size_t)(s & 511) * 65536;

      if (role == 0) {
        // a-waves: gate on CA[s] (LA ~255 ahead => first-poll hit)
        mb_wait(MB, 1 * 64 + jt, s + 1, 1 * 64 + jt, s + 1, lane);
        vmwait<0>();
        stream16<2>(acc, wgt, asrc, half * 32, rl, kg);
      } else {
        // h-waves: self-gate on CB[s-1], then the critical h-GEMM
        mb_wait(MB, 2 * 64 + jt, s, 2 * 64 + jt, s, lane);
        vmwait<0>();
        stream16<3>(acc, wgt, hsrc, half * 32, rl, kg);
      }

      // cross-wave K-combine (sums a-partials + h-partials)
#pragma unroll
      for (int d = 0; d < 4; ++d) if (d != w)
#pragma unroll
        for (int g = 0; g < 4; ++g) *(f4v*)&cmb[d][w][lane][g * 4] = acc[d][g];
      __syncthreads();
      f4v hsum[4];
#pragma unroll
      for (int g = 0; g < 4; ++g) {
        hsum[g] = acc[w][g];
#pragma unroll
        for (int src = 0; src < 4; ++src) if (src != w) hsum[g] += *(f4v*)&cmb[w][src][lane][g * 4];
      }

      us4v hb4;
#pragma unroll
      for (int rr = 0; rr < 4; ++rr) {
        float hp = hv[rr];
        float rg = 1.f / (1.f + __expf(-(hsum[0][rr] + bir[rr] + bhr[rr])));
        float zg = 1.f / (1.f + __expf(-(hsum[1][rr] + biz[rr] + bhz[rr])));
        float narg = hsum[2][rr] + bin[rr] + rg * (hsum[3][rr] + bhn[rr]);
        float e2 = __expf(2.f * narg);
        float ng = 1.f - 2.f / (e2 + 1.f);
        float nv = (1.f - zg) * ng + zg * hp;
        hv[rr] = 0.1f * hp + 0.9f * nv;
      }
      hb4[0] = f2bf(hv[0]); hb4[1] = f2bf(hv[1]); hb4[2] = f2bf(hv[2]); hb4[3] = f2bf(hv[3]);

      st8c(h1r + (size_t)(s & 255) * 65536 + jt * 1024 + b * 16 + kg * 4, hb4);
      stnt16(out + ((size_t)b * Tn + s) * Hn + j0, hv);
      if (s == Tn - 1) {
        stnt16(out + 67108864u + 65536u + (size_t)b * Hn + j0, hv);
        vmwait<0>();
      } else {
        vmwait<1>();                         // st8c acked; out-store off-chain
      }
      __syncthreads();
      if (tid < 64) {
        __hip_atomic_store(MB + ((2 * 64 + tid) * 64 + jt), s + 1,
                           __ATOMIC_RELAXED, __HIP_MEMORY_SCOPE_AGENT);
        __hip_atomic_store(MB + ((3 * 64 + tid) * 64 + jt), s + 1,
                           __ATOMIC_RELAXED, __HIP_MEMORY_SCOPE_AGENT);
      }
    }
  }
}

extern "C" void kernel_launch(void* const* d_in, const int* in_sizes, int n_in,
                              void* d_out, int out_size, void* d_ws, size_t ws_size,
                              hipStream_t stream) {
  (void)in_sizes; (void)n_in; (void)out_size; (void)ws_size;
  const float* x    = (const float*)d_in[0];
  const float* h0in = (const float*)d_in[1];
  const float* wih0 = (const float*)d_in[2];
  const float* whh0 = (const float*)d_in[3];
  const float* bih0 = (const float*)d_in[4];
  const float* bhh0 = (const float*)d_in[5];
  const float* wih1 = (const float*)d_in[6];
  const float* whh1 = (const float*)d_in[7];
  const float* bih1 = (const float*)d_in[8];
  const float* bhh1 = (const float*)d_in[9];
  float* out = (float*)d_out;
  char* ws = (char*)d_ws;

  cvt_bf16_kernel<<<2048, 256, 0, stream>>>(x, (unsigned short*)(ws + WS_XB), 33554432 / 4);
  init_all<<<528, 256, 0, stream>>>(h0in, ws);
  gru_persist<<<dim3(256), dim3(256), 0, stream>>>(
      h0in, wih0, whh0, bih0, bhh0, wih1, whh1, bih1, bhh1, out, ws);
}